// Round 9
// baseline (201.922 us; speedup 1.0000x reference)
//
#include <hip/hip_runtime.h>

#define N_NODES 50000
#define N_EDGES 800000
#define D 128
#define NBKT 391          // buckets = dst>>7 (128 nodes each), == gemm tiles
#define ACB 196           // phaseAC blocks: 196*4096 = 802816 >= 800000
#define ACCHUNK 4096
#define BKTPAD 2432       // bucket region: Poisson(2048) + 8.5 sigma; clamp on overflow
#define GB 391            // gemm tiles: 391*128 = 50048 >= 50000
#define PB 3125           // aggr blocks: 3125*16 = 50000 (gather needs >=3000 blocks)
#define MAXDEG 64         // per-node row: P(Poisson(16) >= 64) ~ 2e-18
#define CHN 12500         // src-chunk width: 4 chunks x 12500 rows x 256B = 3.2MB <= L2

typedef unsigned int uint32;
typedef unsigned short ushort;
typedef __attribute__((ext_vector_type(8))) short s8v;   // 8 x bf16 bits
typedef __attribute__((ext_vector_type(4))) float f4v;   // MFMA accumulator

__device__ __forceinline__ ushort f2bf(float f) {   // RNE bf16
    unsigned u = __float_as_uint(f);
    u += 0x7FFFu + ((u >> 16) & 1u);
    return (ushort)(u >> 16);
}
__device__ __forceinline__ float bf_lo(uint32 u) { return __uint_as_float(u << 16); }
__device__ __forceinline__ float bf_hi(uint32 u) { return __uint_as_float(u & 0xFFFF0000u); }

// ---- K0: weight transpose/cvt (32 blocks) + zero bucket counters (1 block) ----
__global__ __launch_bounds__(256) void prep_kernel(int* __restrict__ bktCnt,
                                                   const float* __restrict__ W1,
                                                   const float* __restrict__ W2,
                                                   ushort* __restrict__ W1t,
                                                   ushort* __restrict__ W2t) {
    int t = threadIdx.x, blk = blockIdx.x;
    if (blk == 32) {
        for (int i = t; i < NBKT; i += 256) bktCnt[i] = 0;
        return;
    }
    const float* W = (blk >= 16) ? W2 : W1;
    ushort* Wt = (blk >= 16) ? W2t : W1t;
    int fid = (blk & 15) * 256 + t;       // float4 id 0..4095
    int k = fid >> 5;
    int n0 = (fid & 31) * 4;
    float4 w = ((const float4*)W)[fid];
    Wt[(n0 + 0) * D + k] = f2bf(w.x);
    Wt[(n0 + 1) * D + k] = f2bf(w.y);
    Wt[(n0 + 2) * D + k] = f2bf(w.z);
    Wt[(n0 + 3) * D + k] = f2bf(w.w);
}

// ---- K1: fused hist + partition: LDS hist -> ONE global atomic per (block,bucket)
// (77K atomics, ~10x under the measured ~7 atomic/cy device wall) reserving a range
// in bucket b's fixed region; LDS cursors assign unique slots. Order arbitrary. ----
__global__ __launch_bounds__(256) void phaseAC_kernel(const int* __restrict__ src,
                                                      const int* __restrict__ dst,
                                                      int* __restrict__ bktCnt,
                                                      uint32* __restrict__ edgeTmp) {
    __shared__ int lc[NBKT];
    __shared__ int gb[NBKT];
    int t = threadIdx.x, blk = blockIdx.x;
    for (int i = t; i < NBKT; i += 256) lc[i] = 0;
    __syncthreads();
    uint32 ed[16];                         // edges held in registers between passes
    int e0 = blk * ACCHUNK;
    #pragma unroll
    for (int j = 0; j < 16; j++) {
        int e = e0 + t + j * 256;
        uint32 pk = 0xFFFFFFFFu;           // sentinel (valid pk has low16 < 50000)
        if (e < N_EDGES) {
            uint32 s = (uint32)src[e], d = (uint32)dst[e];
            pk = (s << 16) | d;
            atomicAdd(&lc[d >> 7], 1);     // LDS
        }
        ed[j] = pk;
    }
    __syncthreads();
    for (int i = t; i < NBKT; i += 256) {
        int c = lc[i];
        gb[i] = (c > 0) ? atomicAdd(&bktCnt[i], c) : 0;   // global range reserve
        lc[i] = 0;                         // reuse as cursor
    }
    __syncthreads();
    #pragma unroll
    for (int j = 0; j < 16; j++) {
        uint32 pk = ed[j];
        if (pk != 0xFFFFFFFFu) {
            int bkt = (int)(pk & 0xFFFFu) >> 7;
            int r = atomicAdd(&lc[bkt], 1);               // LDS rank
            int idx = gb[bkt] + r;
            if (idx < BKTPAD) edgeTmp[bkt * BKTPAD + idx] = pk;   // clamp ~1e-12
        }
    }
}

// ---- K2 FUSED: per-bucket (node, src-chunk) counting sort -> e16 rows ordered by
// src-chunk + packed per-chunk counts deg4, THEN gemm1 on the same 128 rows ----
__global__ __launch_bounds__(256) void phaseDG_kernel(const uint32* __restrict__ edgeTmp,
                                                      const int* __restrict__ bktCnt,
                                                      int* __restrict__ deg,
                                                      uint32* __restrict__ deg4,
                                                      ushort* __restrict__ e16,
                                                      const float* __restrict__ X,
                                                      const ushort* __restrict__ Wt,
                                                      ushort* __restrict__ Hb) {
    __shared__ int cnt4[128][4];
    __shared__ int cur4[128][4];
    __shared__ float disS[128];
    __shared__ ushort Cs[128 * 136];
    int t = threadIdx.x, b = blockIdx.x;
    int ce = bktCnt[b];
    int cntE = ce < BKTPAD ? ce : BKTPAD;
    int beg = b * BKTPAD, end = beg + cntE;
    if (t < 128) { cnt4[t][0] = 0; cnt4[t][1] = 0; cnt4[t][2] = 0; cnt4[t][3] = 0; }
    __syncthreads();
    for (int p = beg + t; p < end; p += 256) {
        uint32 u = edgeTmp[p];
        int ch = (int)(u >> 16) / CHN;
        atomicAdd(&cnt4[u & 127][ch], 1);
    }
    __syncthreads();
    int node = b * 128 + t;
    if (t < 128) {
        int c0 = cnt4[t][0], c1 = cnt4[t][1], c2 = cnt4[t][2], c3 = cnt4[t][3];
        int tot = c0 + c1 + c2 + c3;
        if (node < N_NODES) {
            deg[node] = tot;
            deg4[node] = (uint32)c0 | ((uint32)c1 << 8) | ((uint32)c2 << 16)
                       | ((uint32)c3 << 24);
        }
        disS[t] = rsqrtf((float)tot + 1.0f);
        cur4[t][0] = 0; cur4[t][1] = c0; cur4[t][2] = c0 + c1; cur4[t][3] = c0 + c1 + c2;
    }
    __syncthreads();
    for (int p = beg + t; p < end; p += 256) {
        uint32 u = edgeTmp[p];
        int loc = u & 127;
        int s = (int)(u >> 16);
        int r = atomicAdd(&cur4[loc][s / CHN], 1);        // slot = chunk prefix + rank
        if (r < MAXDEG) e16[((b * 128 + loc) << 6) + r] = (ushort)s;
    }
    // ---- gemm1: Hb[rows of bucket b] = bf16(disS * (X @ W1)) ----
    int wv = t >> 6, lane = t & 63;
    int q = lane >> 4, m = lane & 15;
    int rbase = b * 128 + wv * 32;
    f4v zero = {0.f, 0.f, 0.f, 0.f};
    f4v acc[2][8];
    #pragma unroll
    for (int mt = 0; mt < 2; mt++)
        #pragma unroll
        for (int n = 0; n < 8; n++) acc[mt][n] = zero;
    #pragma unroll
    for (int kt = 0; kt < 4; kt++) {
        int k0 = kt * 32 + q * 8;
        s8v a[2];
        #pragma unroll
        for (int mt = 0; mt < 2; mt++) {
            int row = rbase + mt * 16 + m;
            if (row >= N_NODES) row = N_NODES - 1;
            const float* xp = X + (size_t)row * D + k0;
            float4 u0 = *(const float4*)xp;
            float4 u1 = *(const float4*)(xp + 4);
            s8v av;
            av[0] = (short)f2bf(u0.x); av[1] = (short)f2bf(u0.y);
            av[2] = (short)f2bf(u0.z); av[3] = (short)f2bf(u0.w);
            av[4] = (short)f2bf(u1.x); av[5] = (short)f2bf(u1.y);
            av[6] = (short)f2bf(u1.z); av[7] = (short)f2bf(u1.w);
            a[mt] = av;
        }
        #pragma unroll
        for (int n = 0; n < 8; n++) {
            s8v bb = *(const s8v*)(Wt + (size_t)(n * 16 + m) * D + k0);
            acc[0][n] = __builtin_amdgcn_mfma_f32_16x16x32_bf16(a[0], bb, acc[0][n], 0, 0, 0);
            acc[1][n] = __builtin_amdgcn_mfma_f32_16x16x32_bf16(a[1], bb, acc[1][n], 0, 0, 0);
        }
    }
    __syncthreads();   // sort pass done; Cs free
    #pragma unroll
    for (int mt = 0; mt < 2; mt++)
        #pragma unroll
        for (int n = 0; n < 8; n++)
            #pragma unroll
            for (int r = 0; r < 4; r++) {
                int lr = wv * 32 + mt * 16 + q * 4 + r;
                Cs[lr * 136 + n * 16 + m] = f2bf(acc[mt][n][r] * disS[lr]);
            }
    __syncthreads();
    int gbase = b * 128;
    #pragma unroll
    for (int it = 0; it < 8; it++) {
        int cid = t + it * 256;
        int row = cid >> 4, off = (cid & 15) * 8;
        int grow = gbase + row;
        if (grow < N_NODES) {
            s8v v = *(const s8v*)(Cs + row * 136 + off);
            *(s8v*)(Hb + (size_t)grow * D + off) = v;
        }
    }
}

// ---- standalone gemm2: Hb2 = bf16(dis * (HO1 @ W2)), bf16 input, dis=rsqrt(deg+1) ----
__global__ __launch_bounds__(256) void gemm_mfma(const ushort* __restrict__ Xb,
                                                 const ushort* __restrict__ Wt,
                                                 const int* __restrict__ deg,
                                                 ushort* __restrict__ Hb) {
    __shared__ ushort Cs[128 * 136];
    int t = threadIdx.x;
    int wv = t >> 6, lane = t & 63;
    int q = lane >> 4, m = lane & 15;
    int rbase = blockIdx.x * 128 + wv * 32;
    f4v zero = {0.f, 0.f, 0.f, 0.f};
    f4v acc[2][8];
    #pragma unroll
    for (int mt = 0; mt < 2; mt++)
        #pragma unroll
        for (int n = 0; n < 8; n++) acc[mt][n] = zero;

    #pragma unroll
    for (int kt = 0; kt < 4; kt++) {
        int k0 = kt * 32 + q * 8;
        s8v a[2];
        #pragma unroll
        for (int mt = 0; mt < 2; mt++) {
            int row = rbase + mt * 16 + m;
            if (row >= N_NODES) row = N_NODES - 1;
            a[mt] = *(const s8v*)(Xb + (size_t)row * D + k0);   // 16B load
        }
        #pragma unroll
        for (int n = 0; n < 8; n++) {
            s8v b = *(const s8v*)(Wt + (size_t)(n * 16 + m) * D + k0);
            acc[0][n] = __builtin_amdgcn_mfma_f32_16x16x32_bf16(a[0], b, acc[0][n], 0, 0, 0);
            acc[1][n] = __builtin_amdgcn_mfma_f32_16x16x32_bf16(a[1], b, acc[1][n], 0, 0, 0);
        }
    }
    float disv[2][4];
    #pragma unroll
    for (int mt = 0; mt < 2; mt++)
        #pragma unroll
        for (int r = 0; r < 4; r++) {
            int row = rbase + mt * 16 + q * 4 + r;
            if (row >= N_NODES) row = N_NODES - 1;
            disv[mt][r] = rsqrtf((float)deg[row] + 1.0f);
        }
    #pragma unroll
    for (int mt = 0; mt < 2; mt++)
        #pragma unroll
        for (int n = 0; n < 8; n++)
            #pragma unroll
            for (int r = 0; r < 4; r++) {
                int row = wv * 32 + mt * 16 + q * 4 + r;
                Cs[row * 136 + n * 16 + m] = f2bf(acc[mt][n][r] * disv[mt][r]);
            }
    __syncthreads();
    int gbase = blockIdx.x * 128;
    #pragma unroll
    for (int it = 0; it < 8; it++) {
        int cid = t + it * 256;
        int row = cid >> 4, off = (cid & 15) * 8;
        int grow = gbase + row;
        if (grow < N_NODES) {
            s8v v = *(const s8v*)(Cs + row * 136 + off);
            *(s8v*)(Hb + (size_t)grow * D + off) = v;
        }
    }
}

// ---- aggregate: out = relu(dis[n]*(Hb[n]+sum Hb[src])+b), 16 lanes/node ----
// 4 src-chunk passes: each pass's gathers fall in a 3.2MB Hb window (fits per-XCD
// L2 -> ~2 touches/line reuse). Full 256B-row requests (quartering the CHANNELS
// measured 2x worse; this chunks the gather ORDER only). 3125 blocks, ~2048
// co-resident -> grid stays temporally aligned on the same chunk.
__device__ __forceinline__ void acc8(float* a, uint4 v) {
    a[0] += bf_lo(v.x); a[1] += bf_hi(v.x);
    a[2] += bf_lo(v.y); a[3] += bf_hi(v.y);
    a[4] += bf_lo(v.z); a[5] += bf_hi(v.z);
    a[6] += bf_lo(v.w); a[7] += bf_hi(v.w);
}

template<bool BF16OUT>
__global__ __launch_bounds__(256) void aggr_kernel(const uint4* __restrict__ Hb4,
                                                   const uint32* __restrict__ deg4v,
                                                   const ushort* __restrict__ e16,
                                                   const float* __restrict__ bias,
                                                   void* __restrict__ Hout) {
    int t = threadIdx.x;
    int li = t & 15;                       // lane in group: channels li*8..li*8+7
    int n = blockIdx.x * 16 + (t >> 4);    // 50000 = 3125*16
    uint32 d4 = deg4v[n];
    int cc0 = d4 & 255, cc1 = (d4 >> 8) & 255, cc2 = (d4 >> 16) & 255, cc3 = d4 >> 24;
    int tot = cc0 + cc1 + cc2 + cc3;
    float dn = rsqrtf((float)tot + 1.0f);
    float a[8];
    {
        uint4 sv = Hb4[(size_t)n * 16 + li];   // self term (dis[n] folded into Hb)
        a[0] = bf_lo(sv.x); a[1] = bf_hi(sv.x);
        a[2] = bf_lo(sv.y); a[3] = bf_hi(sv.y);
        a[4] = bf_lo(sv.z); a[5] = bf_hi(sv.z);
        a[6] = bf_lo(sv.w); a[7] = bf_hi(sv.w);
    }
    int beg = n << 6;                      // fixed-stride row base (MAXDEG=64)
    int cap = beg + MAXDEG;
    int cc[4] = {cc0, cc1, cc2, cc3};
    int p = beg;
    #pragma unroll 1
    for (int ch = 0; ch < 4; ch++) {       // same pass order across the whole grid
        int e2 = p + cc[ch];
        if (e2 > cap) e2 = cap;
        for (; p + 3 < e2; p += 4) {       // 4 outstanding 16B gathers per lane
            int s0 = e16[p + 0], s1 = e16[p + 1], s2 = e16[p + 2], s3 = e16[p + 3];
            uint4 v0 = Hb4[(size_t)s0 * 16 + li];
            uint4 v1 = Hb4[(size_t)s1 * 16 + li];
            uint4 v2 = Hb4[(size_t)s2 * 16 + li];
            uint4 v3 = Hb4[(size_t)s3 * 16 + li];
            acc8(a, v0); acc8(a, v1); acc8(a, v2); acc8(a, v3);
        }
        for (; p < e2; p++) {
            uint4 v0 = Hb4[(size_t)e16[p] * 16 + li];
            acc8(a, v0);
        }
    }
    const float4* b4 = (const float4*)bias;
    float4 bb0 = b4[li * 2], bb1 = b4[li * 2 + 1];
    float r0 = fmaxf(fmaf(dn, a[0], bb0.x), 0.f);
    float r1 = fmaxf(fmaf(dn, a[1], bb0.y), 0.f);
    float r2 = fmaxf(fmaf(dn, a[2], bb0.z), 0.f);
    float r3 = fmaxf(fmaf(dn, a[3], bb0.w), 0.f);
    float r4 = fmaxf(fmaf(dn, a[4], bb1.x), 0.f);
    float r5 = fmaxf(fmaf(dn, a[5], bb1.y), 0.f);
    float r6 = fmaxf(fmaf(dn, a[6], bb1.z), 0.f);
    float r7 = fmaxf(fmaf(dn, a[7], bb1.w), 0.f);
    if (BF16OUT) {
        uint4 o;
        o.x = (uint32)f2bf(r0) | ((uint32)f2bf(r1) << 16);
        o.y = (uint32)f2bf(r2) | ((uint32)f2bf(r3) << 16);
        o.z = (uint32)f2bf(r4) | ((uint32)f2bf(r5) << 16);
        o.w = (uint32)f2bf(r6) | ((uint32)f2bf(r7) << 16);
        ((uint4*)Hout)[(size_t)n * 16 + li] = o;
    } else {
        float4* H4 = (float4*)Hout;
        float4 o0; o0.x = r0; o0.y = r1; o0.z = r2; o0.w = r3;
        float4 o1; o1.x = r4; o1.y = r5; o1.z = r6; o1.w = r7;
        H4[(size_t)n * 32 + li * 2]     = o0;
        H4[(size_t)n * 32 + li * 2 + 1] = o1;
    }
}

extern "C" void kernel_launch(void* const* d_in, const int* in_sizes, int n_in,
                              void* d_out, int out_size, void* d_ws, size_t ws_size,
                              hipStream_t stream) {
    const float* x  = (const float*)d_in[0];
    const int*   ei = (const int*)d_in[1];   // int32 per harness contract
    const float* W1 = (const float*)d_in[2];
    const float* b1 = (const float*)d_in[3];
    const float* W2 = (const float*)d_in[4];
    const float* b2 = (const float*)d_in[5];
    float* out = (float*)d_out;

    char* ws = (char*)d_ws;
    size_t off = 0;
    auto alloc = [&](size_t bytes) -> void* {
        void* p = ws + off;
        off += (bytes + 255) & ~(size_t)255;
        return p;
    };
    int*    bktCnt  = (int*)alloc((size_t)NBKT * 4);
    uint32* edgeTmp = (uint32*)alloc((size_t)NBKT * BKTPAD * 4);   // 3.8 MB padded
    int*    deg     = (int*)alloc((size_t)N_NODES * 4);
    uint32* deg4    = (uint32*)alloc((size_t)N_NODES * 4);
    ushort* e16     = (ushort*)alloc((size_t)N_NODES * MAXDEG * 2); // 6.4 MB
    ushort* Hb      = (ushort*)alloc((size_t)N_NODES * D * 2);
    ushort* HO1     = (ushort*)alloc((size_t)N_NODES * D * 2);      // layer-1 out bf16
    ushort* W1t     = (ushort*)alloc((size_t)D * D * 2);
    ushort* W2t     = (ushort*)alloc((size_t)D * D * 2);
    ushort* Hb2     = Hb;            // Hb dead after aggr1; reuse for layer-2 gemm out

    const int* src = ei;             // edge_index[0]
    const int* dst = ei + N_EDGES;   // edge_index[1]

    prep_kernel<<<33, 256, 0, stream>>>(bktCnt, W1, W2, W1t, W2t);
    phaseAC_kernel<<<ACB, 256, 0, stream>>>(src, dst, bktCnt, edgeTmp);
    phaseDG_kernel<<<NBKT, 256, 0, stream>>>(edgeTmp, bktCnt, deg, deg4, e16,
                                             x, W1t, Hb);
    aggr_kernel<true><<<PB, 256, 0, stream>>>((const uint4*)Hb, deg4, e16, b1, HO1);
    gemm_mfma<<<GB, 256, 0, stream>>>(HO1, W2t, deg, Hb2);
    aggr_kernel<false><<<PB, 256, 0, stream>>>((const uint4*)Hb2, deg4, e16, b2, out);
}

// Round 10
// 188.995 us; speedup vs baseline: 1.0684x; 1.0684x over previous
//
#include <hip/hip_runtime.h>

#define N_NODES 50000
#define N_EDGES 800000
#define D 128
#define NBKT 391          // buckets = dst>>7 (128 nodes each), == gemm tiles
#define ACB 196           // phaseAC blocks: 196*4096 = 802816 >= 800000
#define ACCHUNK 4096
#define BKTPAD 2432       // bucket region: Poisson(2048) + 8.5 sigma; clamp on overflow
#define PB 3125           // aggr blocks: 3125*16 = 50000 (gather needs >=3000 blocks)
#define MAXDEG 64         // per-node row: P(Poisson(16) >= 64) ~ 2e-18

typedef unsigned int uint32;
typedef unsigned short ushort;
typedef __attribute__((ext_vector_type(8))) short s8v;   // 8 x bf16 bits
typedef __attribute__((ext_vector_type(4))) float f4v;   // MFMA accumulator

__device__ __forceinline__ ushort f2bf(float f) {   // RNE bf16
    unsigned u = __float_as_uint(f);
    u += 0x7FFFu + ((u >> 16) & 1u);
    return (ushort)(u >> 16);
}
__device__ __forceinline__ float bf_lo(uint32 u) { return __uint_as_float(u << 16); }
__device__ __forceinline__ float bf_hi(uint32 u) { return __uint_as_float(u & 0xFFFF0000u); }

// ---- K0: weight transpose/cvt (32 blocks) + zero bucket counters (1 block) ----
__global__ __launch_bounds__(256) void prep_kernel(int* __restrict__ bktCnt,
                                                   const float* __restrict__ W1,
                                                   const float* __restrict__ W2,
                                                   ushort* __restrict__ W1t,
                                                   ushort* __restrict__ W2t) {
    int t = threadIdx.x, blk = blockIdx.x;
    if (blk == 32) {
        for (int i = t; i < NBKT; i += 256) bktCnt[i] = 0;
        return;
    }
    const float* W = (blk >= 16) ? W2 : W1;
    ushort* Wt = (blk >= 16) ? W2t : W1t;
    int fid = (blk & 15) * 256 + t;       // float4 id 0..4095
    int k = fid >> 5;
    int n0 = (fid & 31) * 4;
    float4 w = ((const float4*)W)[fid];
    Wt[(n0 + 0) * D + k] = f2bf(w.x);
    Wt[(n0 + 1) * D + k] = f2bf(w.y);
    Wt[(n0 + 2) * D + k] = f2bf(w.z);
    Wt[(n0 + 3) * D + k] = f2bf(w.w);
}

// ---- K1: fused hist + partition: LDS hist -> ONE global atomic per (block,bucket)
// (77K atomics, ~10x under the measured ~7 atomic/cy device wall) reserving a range
// in bucket b's fixed region; LDS cursors assign unique slots. Order arbitrary. ----
__global__ __launch_bounds__(256) void phaseAC_kernel(const int* __restrict__ src,
                                                      const int* __restrict__ dst,
                                                      int* __restrict__ bktCnt,
                                                      uint32* __restrict__ edgeTmp) {
    __shared__ int lc[NBKT];
    __shared__ int gb[NBKT];
    int t = threadIdx.x, blk = blockIdx.x;
    for (int i = t; i < NBKT; i += 256) lc[i] = 0;
    __syncthreads();
    uint32 ed[16];                         // edges held in registers between passes
    int e0 = blk * ACCHUNK;
    #pragma unroll
    for (int j = 0; j < 16; j++) {
        int e = e0 + t + j * 256;
        uint32 pk = 0xFFFFFFFFu;           // sentinel (valid pk has low16 < 50000)
        if (e < N_EDGES) {
            uint32 s = (uint32)src[e], d = (uint32)dst[e];
            pk = (s << 16) | d;
            atomicAdd(&lc[d >> 7], 1);     // LDS
        }
        ed[j] = pk;
    }
    __syncthreads();
    for (int i = t; i < NBKT; i += 256) {
        int c = lc[i];
        gb[i] = (c > 0) ? atomicAdd(&bktCnt[i], c) : 0;   // global range reserve
        lc[i] = 0;                         // reuse as cursor
    }
    __syncthreads();
    #pragma unroll
    for (int j = 0; j < 16; j++) {
        uint32 pk = ed[j];
        if (pk != 0xFFFFFFFFu) {
            int bkt = (int)(pk & 0xFFFFu) >> 7;
            int r = atomicAdd(&lc[bkt], 1);               // LDS rank
            int idx = gb[bkt] + r;
            if (idx < BKTPAD) edgeTmp[bkt * BKTPAD + idx] = pk;   // clamp ~1e-12
        }
    }
}

// ---- K2 FUSED: per-bucket counting sort -> e16 fixed rows + deg, THEN gemm1 on
// the same 128 rows (bucket b == gemm tile b; dis from LDS, never re-read) ----
__global__ __launch_bounds__(256) void phaseDG_kernel(const uint32* __restrict__ edgeTmp,
                                                      const int* __restrict__ bktCnt,
                                                      int* __restrict__ deg,
                                                      ushort* __restrict__ e16,
                                                      const float* __restrict__ X,
                                                      const ushort* __restrict__ Wt,
                                                      ushort* __restrict__ Hb) {
    __shared__ int cnt[128];
    __shared__ int cur[128];
    __shared__ float disS[128];
    __shared__ ushort Cs[128 * 136];
    int t = threadIdx.x, b = blockIdx.x;
    int ce = bktCnt[b];
    int cntE = ce < BKTPAD ? ce : BKTPAD;
    int beg = b * BKTPAD, end = beg + cntE;
    if (t < 128) { cnt[t] = 0; cur[t] = 0; }
    __syncthreads();
    for (int p = beg + t; p < end; p += 256)
        atomicAdd(&cnt[edgeTmp[p] & 127], 1);
    __syncthreads();
    int node = b * 128 + t;
    if (t < 128) {
        int c = cnt[t];
        if (node < N_NODES) deg[node] = c;
        disS[t] = rsqrtf((float)c + 1.0f);
    }
    __syncthreads();
    for (int p = beg + t; p < end; p += 256) {
        uint32 u = edgeTmp[p];
        int loc = u & 127;
        int r = atomicAdd(&cur[loc], 1);                  // LDS
        if (r < MAXDEG) e16[((b * 128 + loc) << 6) + r] = (ushort)(u >> 16);
    }
    // ---- gemm1: Hb[rows of bucket b] = bf16(disS * (X @ W1)) ----
    int wv = t >> 6, lane = t & 63;
    int q = lane >> 4, m = lane & 15;
    int rbase = b * 128 + wv * 32;
    f4v zero = {0.f, 0.f, 0.f, 0.f};
    f4v acc[2][8];
    #pragma unroll
    for (int mt = 0; mt < 2; mt++)
        #pragma unroll
        for (int n = 0; n < 8; n++) acc[mt][n] = zero;
    #pragma unroll
    for (int kt = 0; kt < 4; kt++) {
        int k0 = kt * 32 + q * 8;
        s8v a[2];
        #pragma unroll
        for (int mt = 0; mt < 2; mt++) {
            int row = rbase + mt * 16 + m;
            if (row >= N_NODES) row = N_NODES - 1;
            const float* xp = X + (size_t)row * D + k0;
            float4 u0 = *(const float4*)xp;
            float4 u1 = *(const float4*)(xp + 4);
            s8v av;
            av[0] = (short)f2bf(u0.x); av[1] = (short)f2bf(u0.y);
            av[2] = (short)f2bf(u0.z); av[3] = (short)f2bf(u0.w);
            av[4] = (short)f2bf(u1.x); av[5] = (short)f2bf(u1.y);
            av[6] = (short)f2bf(u1.z); av[7] = (short)f2bf(u1.w);
            a[mt] = av;
        }
        #pragma unroll
        for (int n = 0; n < 8; n++) {
            s8v bb = *(const s8v*)(Wt + (size_t)(n * 16 + m) * D + k0);
            acc[0][n] = __builtin_amdgcn_mfma_f32_16x16x32_bf16(a[0], bb, acc[0][n], 0, 0, 0);
            acc[1][n] = __builtin_amdgcn_mfma_f32_16x16x32_bf16(a[1], bb, acc[1][n], 0, 0, 0);
        }
    }
    __syncthreads();   // sort pass done; Cs free
    #pragma unroll
    for (int mt = 0; mt < 2; mt++)
        #pragma unroll
        for (int n = 0; n < 8; n++)
            #pragma unroll
            for (int r = 0; r < 4; r++) {
                int lr = wv * 32 + mt * 16 + q * 4 + r;
                Cs[lr * 136 + n * 16 + m] = f2bf(acc[mt][n][r] * disS[lr]);
            }
    __syncthreads();
    int gbase = b * 128;
    #pragma unroll
    for (int it = 0; it < 8; it++) {
        int cid = t + it * 256;
        int row = cid >> 4, off = (cid & 15) * 8;
        int grow = gbase + row;
        if (grow < N_NODES) {
            s8v v = *(const s8v*)(Cs + row * 136 + off);
            *(s8v*)(Hb + (size_t)grow * D + off) = v;
        }
    }
}

// ---- helpers ----
__device__ __forceinline__ void acc8(float* a, uint4 v) {
    a[0] += bf_lo(v.x); a[1] += bf_hi(v.x);
    a[2] += bf_lo(v.y); a[3] += bf_hi(v.y);
    a[4] += bf_lo(v.z); a[5] += bf_hi(v.z);
    a[6] += bf_lo(v.w); a[7] += bf_hi(v.w);
}

// ---- K3 FUSED: aggr layer-1 + gemm2, at PB=3125 blocks (16 nodes/block).
// Unlike the failed R4 fusion (which dragged the GATHER to 391 blocks), this keeps
// the gather at full grid depth and adds the tiny per-block MFMA tail: 16 HO1 rows
// (held in LDS, never in HBM) x W2t = 32 MFMAs/block, hidden under gather latency.
// W2t (32KB) is L2-hot per XCD. Saves gemm2 dispatch + 25.6MB HO1 round-trip. ----
__global__ __launch_bounds__(256) void aggrW2_kernel(const uint4* __restrict__ Hb4,
                                                     const int* __restrict__ deg,
                                                     const ushort* __restrict__ e16,
                                                     const float* __restrict__ bias,
                                                     const ushort* __restrict__ Wt,
                                                     ushort* __restrict__ Hb2) {
    __shared__ ushort Hs[16 * 136];        // relu'd HO1 rows (bf16)
    __shared__ ushort Cs[16 * 136];        // gemm2 output staging
    __shared__ float disS[16];
    int t = threadIdx.x;
    int li = t & 15, g = t >> 4;           // 16 lanes per node, 16 nodes
    int n = blockIdx.x * 16 + g;           // 3125*16 = 50000 exactly
    int dg = deg[n];
    float dn = rsqrtf((float)dg + 1.0f);
    if (li == 0) disS[g] = dn;
    float a[8];
    {
        uint4 sv = Hb4[(size_t)n * 16 + li];   // self term (dis folded into Hb)
        a[0] = bf_lo(sv.x); a[1] = bf_hi(sv.x);
        a[2] = bf_lo(sv.y); a[3] = bf_hi(sv.y);
        a[4] = bf_lo(sv.z); a[5] = bf_hi(sv.z);
        a[6] = bf_lo(sv.w); a[7] = bf_hi(sv.w);
    }
    int beg = n << 6;                      // fixed-stride row base (MAXDEG=64)
    int end = beg + (dg < MAXDEG ? dg : MAXDEG);
    int p = beg;
    for (; p + 7 < end; p += 8) {          // 8 outstanding 16B gathers per lane
        int s[8];
        #pragma unroll
        for (int j = 0; j < 8; j++) s[j] = e16[p + j];
        uint4 v[8];
        #pragma unroll
        for (int j = 0; j < 8; j++) v[j] = Hb4[(size_t)s[j] * 16 + li];
        #pragma unroll
        for (int j = 0; j < 8; j++) acc8(a, v[j]);
    }
    for (; p + 3 < end; p += 4) {
        int s0 = e16[p + 0], s1 = e16[p + 1], s2 = e16[p + 2], s3 = e16[p + 3];
        uint4 v0 = Hb4[(size_t)s0 * 16 + li];
        uint4 v1 = Hb4[(size_t)s1 * 16 + li];
        uint4 v2 = Hb4[(size_t)s2 * 16 + li];
        uint4 v3 = Hb4[(size_t)s3 * 16 + li];
        acc8(a, v0); acc8(a, v1); acc8(a, v2); acc8(a, v3);
    }
    for (; p < end; p++) {
        uint4 v0 = Hb4[(size_t)e16[p] * 16 + li];
        acc8(a, v0);
    }
    const float4* b4 = (const float4*)bias;
    float4 bb0 = b4[li * 2], bb1 = b4[li * 2 + 1];
    s8v o;
    o[0] = (short)f2bf(fmaxf(fmaf(dn, a[0], bb0.x), 0.f));
    o[1] = (short)f2bf(fmaxf(fmaf(dn, a[1], bb0.y), 0.f));
    o[2] = (short)f2bf(fmaxf(fmaf(dn, a[2], bb0.z), 0.f));
    o[3] = (short)f2bf(fmaxf(fmaf(dn, a[3], bb0.w), 0.f));
    o[4] = (short)f2bf(fmaxf(fmaf(dn, a[4], bb1.x), 0.f));
    o[5] = (short)f2bf(fmaxf(fmaf(dn, a[5], bb1.y), 0.f));
    o[6] = (short)f2bf(fmaxf(fmaf(dn, a[6], bb1.z), 0.f));
    o[7] = (short)f2bf(fmaxf(fmaf(dn, a[7], bb1.w), 0.f));
    *(s8v*)(Hs + g * 136 + li * 8) = o;    // HO1 row -> LDS only
    __syncthreads();
    // ---- gemm2 tail: Hb2[16 rows] = bf16(disS * (Hs @ W2t)); 8 MFMAs/wave ----
    int wv = t >> 6, lane = t & 63;
    int q = lane >> 4, m = lane & 15;
    f4v zero = {0.f, 0.f, 0.f, 0.f};
    f4v acc[2] = {zero, zero};
    #pragma unroll
    for (int kt = 0; kt < 4; kt++) {
        int k0 = kt * 32 + q * 8;
        s8v av = *(const s8v*)(Hs + m * 136 + k0);
        #pragma unroll
        for (int nt = 0; nt < 2; nt++) {
            int col0 = (wv * 2 + nt) * 16;
            s8v bv = *(const s8v*)(Wt + (size_t)(col0 + m) * D + k0);
            acc[nt] = __builtin_amdgcn_mfma_f32_16x16x32_bf16(av, bv, acc[nt], 0, 0, 0);
        }
    }
    #pragma unroll
    for (int nt = 0; nt < 2; nt++)
        #pragma unroll
        for (int r = 0; r < 4; r++) {
            int row = q * 4 + r;           // C layout: col=lane&15, row=(lane>>4)*4+r
            Cs[row * 136 + (wv * 2 + nt) * 16 + m] = f2bf(acc[nt][r] * disS[row]);
        }
    __syncthreads();
    int row = t >> 4, off = (t & 15) * 8;  // coalesced 4KB block write
    *(s8v*)(Hb2 + (size_t)(blockIdx.x * 16 + row) * D + off) =
        *(const s8v*)(Cs + row * 136 + off);
}

// ---- K4: final aggregate: out = relu(dis[n]*(Hb2[n]+sum Hb2[src])+b2), f32 out ----
__global__ __launch_bounds__(256) void aggr_kernel(const uint4* __restrict__ Hb4,
                                                   const int* __restrict__ deg,
                                                   const ushort* __restrict__ e16,
                                                   const float* __restrict__ bias,
                                                   float* __restrict__ Hout) {
    int t = threadIdx.x;
    int li = t & 15;                       // lane in group: channels li*8..li*8+7
    int n = blockIdx.x * 16 + (t >> 4);    // 50000 = 3125*16
    int dg = deg[n];
    float dn = rsqrtf((float)dg + 1.0f);
    float a[8];
    {
        uint4 sv = Hb4[(size_t)n * 16 + li];   // self term (dis folded into Hb2)
        a[0] = bf_lo(sv.x); a[1] = bf_hi(sv.x);
        a[2] = bf_lo(sv.y); a[3] = bf_hi(sv.y);
        a[4] = bf_lo(sv.z); a[5] = bf_hi(sv.z);
        a[6] = bf_lo(sv.w); a[7] = bf_hi(sv.w);
    }
    int beg = n << 6;                      // fixed-stride row base (MAXDEG=64)
    int end = beg + (dg < MAXDEG ? dg : MAXDEG);
    int p = beg;
    for (; p + 7 < end; p += 8) {          // 8 outstanding 16B gathers per lane
        int s[8];
        #pragma unroll
        for (int j = 0; j < 8; j++) s[j] = e16[p + j];
        uint4 v[8];
        #pragma unroll
        for (int j = 0; j < 8; j++) v[j] = Hb4[(size_t)s[j] * 16 + li];
        #pragma unroll
        for (int j = 0; j < 8; j++) acc8(a, v[j]);
    }
    for (; p + 3 < end; p += 4) {
        int s0 = e16[p + 0], s1 = e16[p + 1], s2 = e16[p + 2], s3 = e16[p + 3];
        uint4 v0 = Hb4[(size_t)s0 * 16 + li];
        uint4 v1 = Hb4[(size_t)s1 * 16 + li];
        uint4 v2 = Hb4[(size_t)s2 * 16 + li];
        uint4 v3 = Hb4[(size_t)s3 * 16 + li];
        acc8(a, v0); acc8(a, v1); acc8(a, v2); acc8(a, v3);
    }
    for (; p < end; p++) {
        uint4 v0 = Hb4[(size_t)e16[p] * 16 + li];
        acc8(a, v0);
    }
    const float4* b4 = (const float4*)bias;
    float4 bb0 = b4[li * 2], bb1 = b4[li * 2 + 1];
    float4 o0, o1;
    o0.x = fmaxf(fmaf(dn, a[0], bb0.x), 0.f);
    o0.y = fmaxf(fmaf(dn, a[1], bb0.y), 0.f);
    o0.z = fmaxf(fmaf(dn, a[2], bb0.z), 0.f);
    o0.w = fmaxf(fmaf(dn, a[3], bb0.w), 0.f);
    o1.x = fmaxf(fmaf(dn, a[4], bb1.x), 0.f);
    o1.y = fmaxf(fmaf(dn, a[5], bb1.y), 0.f);
    o1.z = fmaxf(fmaf(dn, a[6], bb1.z), 0.f);
    o1.w = fmaxf(fmaf(dn, a[7], bb1.w), 0.f);
    float4* H4 = (float4*)Hout;
    H4[(size_t)n * 32 + li * 2]     = o0;
    H4[(size_t)n * 32 + li * 2 + 1] = o1;
}

extern "C" void kernel_launch(void* const* d_in, const int* in_sizes, int n_in,
                              void* d_out, int out_size, void* d_ws, size_t ws_size,
                              hipStream_t stream) {
    const float* x  = (const float*)d_in[0];
    const int*   ei = (const int*)d_in[1];   // int32 per harness contract
    const float* W1 = (const float*)d_in[2];
    const float* b1 = (const float*)d_in[3];
    const float* W2 = (const float*)d_in[4];
    const float* b2 = (const float*)d_in[5];
    float* out = (float*)d_out;

    char* ws = (char*)d_ws;
    size_t off = 0;
    auto alloc = [&](size_t bytes) -> void* {
        void* p = ws + off;
        off += (bytes + 255) & ~(size_t)255;
        return p;
    };
    int*    bktCnt  = (int*)alloc((size_t)NBKT * 4);
    uint32* edgeTmp = (uint32*)alloc((size_t)NBKT * BKTPAD * 4);   // 3.8 MB padded
    int*    deg     = (int*)alloc((size_t)N_NODES * 4);
    ushort* e16     = (ushort*)alloc((size_t)N_NODES * MAXDEG * 2); // 6.4 MB
    ushort* Hb      = (ushort*)alloc((size_t)N_NODES * D * 2);      // layer-1 gemm out
    ushort* Hb2     = (ushort*)alloc((size_t)N_NODES * D * 2);      // layer-2 gemm out
    ushort* W1t     = (ushort*)alloc((size_t)D * D * 2);
    ushort* W2t     = (ushort*)alloc((size_t)D * D * 2);

    const int* src = ei;             // edge_index[0]
    const int* dst = ei + N_EDGES;   // edge_index[1]

    prep_kernel<<<33, 256, 0, stream>>>(bktCnt, W1, W2, W1t, W2t);
    phaseAC_kernel<<<ACB, 256, 0, stream>>>(src, dst, bktCnt, edgeTmp);
    phaseDG_kernel<<<NBKT, 256, 0, stream>>>(edgeTmp, bktCnt, deg, e16, x, W1t, Hb);
    aggrW2_kernel<<<PB, 256, 0, stream>>>((const uint4*)Hb, deg, e16, b1, W2t, Hb2);
    aggr_kernel<<<PB, 256, 0, stream>>>((const uint4*)Hb2, deg, e16, b2, out);
}